// Round 5
// baseline (885.888 us; speedup 1.0000x reference)
//
#include <hip/hip_runtime.h>
#include <hip/hip_bf16.h>

typedef __attribute__((ext_vector_type(8))) short bf16x8;
typedef __attribute__((ext_vector_type(4))) float f32x4;
typedef __attribute__((ext_vector_type(8))) unsigned short u16x8;

__device__ __forceinline__ unsigned short f2bf(float f) {
  union { float f; unsigned u; } c; c.f = f;
  unsigned u = c.u;
  u = (u + 0x7FFFu + ((u >> 16) & 1u)) >> 16;   // RNE
  return (unsigned short)u;
}

__device__ __forceinline__ void gld_lds16(const void* g, void* l) {
  __builtin_amdgcn_global_load_lds(
      (__attribute__((address_space(1))) unsigned int*)g,
      (__attribute__((address_space(3))) unsigned int*)l,
      16, 0, 0);
}

// ---------------- single fused conversion kernel (round-2 version) ---------
__global__ void cvt_all(const float* __restrict__ x, unsigned short* __restrict__ x16,
                        const float* __restrict__ Kw, unsigned short* __restrict__ K16,
                        const float* __restrict__ V, unsigned short* __restrict__ Vt,
                        float* __restrict__ lsum) {
  const int b = blockIdx.x;
  const int tid = threadIdx.x;
  if (b < 32) lsum[b * 256 + tid] = 0.f;

  if (b < 6144) {
    const float* in;
    unsigned short* out;
    int i;
    if (b < 4096) {
      in = x; out = x16; i = (b * 256 + tid) * 8;
    } else {
      in = Kw; out = K16; i = ((b - 4096) * 256 + tid) * 8;
    }
    const float4* p = (const float4*)(in + i);
    float4 a = p[0], bb = p[1];
    u16x8 r;
    r[0] = f2bf(a.x); r[1] = f2bf(a.y); r[2] = f2bf(a.z); r[3] = f2bf(a.w);
    r[4] = f2bf(bb.x); r[5] = f2bf(bb.y); r[6] = f2bf(bb.z); r[7] = f2bf(bb.w);
    *(u16x8*)(out + i) = r;
  } else {
    __shared__ unsigned short t[64][65];
    const int tile = b - 6144;
    const int p0 = (tile & 63) * 64;
    const int e0 = (tile >> 6) * 64;
    const int tx = tid & 63;
    const int ty = tid >> 6;
#pragma unroll
    for (int i = 0; i < 16; ++i) {
      int p = ty + i * 4;
      t[p][tx] = f2bf(V[(size_t)(p0 + p) * 1024 + e0 + tx]);
    }
    __syncthreads();
    const int op = (tid & 7) * 8;
    const int oe = tid >> 3;
#pragma unroll
    for (int h = 0; h < 2; ++h) {
      int e = oe + h * 32;
      u16x8 r;
#pragma unroll
      for (int i = 0; i < 8; ++i) r[i] = t[op + i][e];
      *(u16x8*)(Vt + (size_t)(e0 + e) * 4096 + p0 + op) = r;
    }
  }
}

// ---- BK=32 double-buffered NT GEMM, counted waits, >=2 resident blocks/CU --
// A [M x Kd], B [N x Kd] row-major bf16. S = A.B^T.
// EPI==0: 256x256 tile, 512 thr (8 waves 2x4), LDS 64KB -> 2 blocks/CU.
//         grid 512 (32m x 16n, XCD-swizzled). P = exp2(scale*S) -> Pout + lsum.
// EPI==1: 128x128 tile, 256 thr (4 waves 2x2), LDS 32KB -> 2+ blocks/CU.
//         grid 512 (64m x 8n, XCD-swizzled). C = S / lin[row].
// Per K-tile (one barrier!): {ds_read frags | stage next tile into other buf
//   -> lgkmcnt(0) -> MFMA (covers staging latency) -> vmcnt(0) -> barrier}.
// LDS rows are 64B (4 chunks), chunk-XOR swizzle ^(row&3); fragment reads are
// 2-way bank aliased (free, m136). Tail staging wraps to tile 0 (harmless).
template <int EPI, int THR>
__global__ __launch_bounds__(THR, 4) void gemm_dp(
    const unsigned short* __restrict__ A, const unsigned short* __restrict__ B,
    unsigned short* __restrict__ Pout, float* __restrict__ lsum,
    float* __restrict__ Cout, const float* __restrict__ lin, float scale) {
  constexpr int BM = EPI ? 128 : 256;    // square tile
  constexpr int Kd = EPI ? 4096 : 1024;
  constexpr int Nc = EPI ? 1024 : 4096;
  constexpr int NT = Kd / 32;            // 128 / 32 K-tiles (pow2)
  constexpr int UB = BM * 64;            // operand tile bytes (BM x 32 x 2B)
  constexpr int MR = EPI ? 4 : 8;        // mi fragments per wave
  constexpr int RSTEP = THR / 4;         // rows covered per staging load

  __shared__ __align__(16) char lds[4 * UB];   // 2 bufs x (A + B)

  const int tid = threadIdx.x;
  const int lane = tid & 63;
  const int w = tid >> 6;
  const int wm = EPI ? (w >> 1) : (w >> 2);
  const int wn = EPI ? (w & 1) : (w & 3);
  const int q = lane >> 4;
  const int ml = lane & 15;

  const int wg = ((blockIdx.x & 7) << 6) + (blockIdx.x >> 3);   // 512 % 8 == 0
  const int m_t = EPI ? (wg >> 3) : (wg >> 4);
  const int n_t = EPI ? (wg & 7) : (wg & 15);
  const int row0 = m_t * BM, col0 = n_t * BM;

  // Staging: LDS chunk c (16B) at row c>>2, slot c&3; slot s of row r holds
  // global k-chunk s^(r&3). Thread stages chunks tid and tid+THR per operand.
  const int r_ = tid >> 2;
  const int s_ = (tid & 3) ^ (r_ & 3);
  const unsigned short* pA = A + (size_t)(row0 + r_) * Kd + s_ * 8;
  const unsigned short* pB = B + (size_t)(col0 + r_) * Kd + s_ * 8;
  char* dw = lds + w * 1024;   // wave-uniform LDS dest base (HW adds lane*16)

  // Fragment reads: row = (wm*BM/2 | wn*64) + x*16 + ml, logical k-chunk = q,
  // swizzled slot = q^(row&3) = q^(ml&3).
  const int cc = (q ^ (ml & 3)) * 16;
  const int aOff = (wm * (BM / 2) + ml) * 64 + cc;        // + mi*1024
  const int bOff = UB + (wn * 64 + ml) * 64 + cc;         // + ni*1024

  f32x4 acc[MR][4] = {};

  // prologue: tile 0 -> buf 0
  gld_lds16(pA, dw);
  gld_lds16(pA + (size_t)RSTEP * Kd, dw + THR * 16);
  gld_lds16(pB, dw + UB);
  gld_lds16(pB + (size_t)RSTEP * Kd, dw + UB + THR * 16);
  asm volatile("s_waitcnt vmcnt(0)" ::: "memory");
  __builtin_amdgcn_s_barrier();
  __builtin_amdgcn_sched_barrier(0);

#pragma unroll 2
  for (int t = 0; t < NT; ++t) {
    const char* base = lds + (t & 1) * (2 * UB);
    char* nb = lds + ((t + 1) & 1) * (2 * UB) + w * 1024;
    const int tn = (t + 1) & (NT - 1);

    bf16x8 aF[MR], bF[4];
#pragma unroll
    for (int mi = 0; mi < MR; ++mi)
      aF[mi] = *(const bf16x8*)(base + aOff + mi * 1024);
#pragma unroll
    for (int ni = 0; ni < 4; ++ni)
      bF[ni] = *(const bf16x8*)(base + bOff + ni * 1024);

    const unsigned short* sA = pA + tn * 32;
    const unsigned short* sB = pB + tn * 32;
    gld_lds16(sA, nb);
    gld_lds16(sA + (size_t)RSTEP * Kd, nb + THR * 16);
    gld_lds16(sB, nb + UB);
    gld_lds16(sB + (size_t)RSTEP * Kd, nb + UB + THR * 16);

    asm volatile("s_waitcnt lgkmcnt(0)" ::: "memory");
    __builtin_amdgcn_sched_barrier(0);
    __builtin_amdgcn_s_setprio(1);
#pragma unroll
    for (int mi = 0; mi < MR; ++mi)
#pragma unroll
      for (int ni = 0; ni < 4; ++ni)
        acc[mi][ni] = __builtin_amdgcn_mfma_f32_16x16x32_bf16(
            aF[mi], bF[ni], acc[mi][ni], 0, 0, 0);
    __builtin_amdgcn_s_setprio(0);
    asm volatile("s_waitcnt vmcnt(0)" ::: "memory");   // my staging landed
    __builtin_amdgcn_s_barrier();                      // everyone's landed
    __builtin_amdgcn_sched_barrier(0);
  }

  if constexpr (EPI == 0) {
#pragma unroll
    for (int mi = 0; mi < MR; ++mi) {
#pragma unroll
      for (int j = 0; j < 4; ++j) {
        const int gr = row0 + wm * (BM / 2) + mi * 16 + q * 4 + j;
        float rsum = 0.f;
#pragma unroll
        for (int ni = 0; ni < 4; ++ni) {
          const int gc = col0 + wn * 64 + ni * 16 + ml;
          float pv = exp2f(acc[mi][ni][j] * scale);  // scale includes log2(e)
          rsum += pv;
          Pout[(size_t)gr * Nc + gc] = f2bf(pv);
        }
        rsum += __shfl_xor(rsum, 1);
        rsum += __shfl_xor(rsum, 2);
        rsum += __shfl_xor(rsum, 4);
        rsum += __shfl_xor(rsum, 8);
        if (ml == 0) atomicAdd(&lsum[gr], rsum);
      }
    }
  } else {
#pragma unroll
    for (int mi = 0; mi < MR; ++mi) {
#pragma unroll
      for (int j = 0; j < 4; ++j) {
        const int gr = row0 + wm * (BM / 2) + mi * 16 + q * 4 + j;
        const float rl = 1.0f / lin[gr];
#pragma unroll
        for (int ni = 0; ni < 4; ++ni) {
          const int gc = col0 + wn * 64 + ni * 16 + ml;
          Cout[(size_t)gr * Nc + gc] = acc[mi][ni][j] * rl;
        }
      }
    }
  }
}

extern "C" void kernel_launch(void* const* d_in, const int* in_sizes, int n_in,
                              void* d_out, int out_size, void* d_ws,
                              size_t ws_size, hipStream_t stream) {
  const float* x = (const float*)d_in[0];   // [8192,1024]
  const float* Kw = (const float*)d_in[1];  // [4096,1024]
  const float* Vw = (const float*)d_in[2];  // [4096,1024]
  float* out = (float*)d_out;               // [8192,1024]
  char* ws = (char*)d_ws;

  unsigned short* x16  = (unsigned short*)(ws);                   // 16 MB
  unsigned short* K16  = (unsigned short*)(ws + (16u << 20));     //  8 MB
  unsigned short* V16t = (unsigned short*)(ws + (24u << 20));     //  8 MB
  float*          lsum = (float*)(ws + (32u << 20));              // 32 KB
  unsigned short* P16  = (unsigned short*)(ws + (33u << 20));     // 64 MB

  cvt_all<<<7168, 256, 0, stream>>>(x, x16, Kw, K16, Vw, V16t, lsum);

  // GEMM1: P = exp(x16 . K16^T / 32), row sums -> lsum.
  gemm_dp<0, 512><<<512, 512, 0, stream>>>(
      x16, K16, P16, lsum, nullptr, nullptr,
      0.03125f * 1.44269504088896340736f);
  // GEMM2: out = (P16 . V16t^T) / lsum[row]
  gemm_dp<1, 256><<<512, 256, 0, stream>>>(
      P16, V16t, nullptr, nullptr, out, lsum, 0.f);
}

// Round 7
// 257.269 us; speedup vs baseline: 3.4434x; 3.4434x over previous
//
#include <hip/hip_runtime.h>
#include <hip/hip_bf16.h>

typedef __attribute__((ext_vector_type(8))) short bf16x8;
typedef __attribute__((ext_vector_type(4))) float f32x4;
typedef __attribute__((ext_vector_type(8))) unsigned short u16x8;

__device__ __forceinline__ unsigned short f2bf(float f) {
  union { float f; unsigned u; } c; c.f = f;
  unsigned u = c.u;
  u = (u + 0x7FFFu + ((u >> 16) & 1u)) >> 16;   // RNE
  return (unsigned short)u;
}

__device__ __forceinline__ void gld_lds16(const void* g, void* l) {
  __builtin_amdgcn_global_load_lds(
      (__attribute__((address_space(1))) unsigned int*)g,
      (__attribute__((address_space(3))) unsigned int*)l,
      16, 0, 0);
}

// Raw workgroup barrier that is also a compiler memory fence (but NOT a
// vmcnt/lgkmcnt drain): memory ops cannot cross it; compiler keeps its own
// fine-grained counted lgkm waits for ds_read->MFMA inside each phase.
#define BAR() asm volatile("s_barrier" ::: "memory")

// ---------------- single fused conversion kernel (round-2 exact) -----------
__global__ void cvt_all(const float* __restrict__ x, unsigned short* __restrict__ x16,
                        const float* __restrict__ Kw, unsigned short* __restrict__ K16,
                        const float* __restrict__ V, unsigned short* __restrict__ Vt,
                        float* __restrict__ lsum) {
  const int b = blockIdx.x;
  const int tid = threadIdx.x;
  if (b < 32) lsum[b * 256 + tid] = 0.f;

  if (b < 6144) {
    const float* in;
    unsigned short* out;
    int i;
    if (b < 4096) {
      in = x; out = x16; i = (b * 256 + tid) * 8;
    } else {
      in = Kw; out = K16; i = ((b - 4096) * 256 + tid) * 8;
    }
    const float4* p = (const float4*)(in + i);
    float4 a = p[0], bb = p[1];
    u16x8 r;
    r[0] = f2bf(a.x); r[1] = f2bf(a.y); r[2] = f2bf(a.z); r[3] = f2bf(a.w);
    r[4] = f2bf(bb.x); r[5] = f2bf(bb.y); r[6] = f2bf(bb.z); r[7] = f2bf(bb.w);
    *(u16x8*)(out + i) = r;
  } else {
    __shared__ unsigned short t[64][65];
    const int tile = b - 6144;
    const int p0 = (tile & 63) * 64;
    const int e0 = (tile >> 6) * 64;
    const int tx = tid & 63;
    const int ty = tid >> 6;
#pragma unroll
    for (int i = 0; i < 16; ++i) {
      int p = ty + i * 4;
      t[p][tx] = f2bf(V[(size_t)(p0 + p) * 1024 + e0 + tx]);
    }
    __syncthreads();
    const int op = (tid & 7) * 8;
    const int oe = tid >> 3;
#pragma unroll
    for (int h = 0; h < 2; ++h) {
      int e = oe + h * 32;
      u16x8 r;
#pragma unroll
      for (int i = 0; i < 8; ++i) r[i] = t[op + i][e];
      *(u16x8*)(Vt + (size_t)(e0 + e) * 4096 + p0 + op) = r;
    }
  }
}

// ---- 8-phase NT GEMM, DE-PINNED: no sched_barrier, no manual lgkmcnt ------
// A [M x Kd], B [N x Kd] row-major bf16. S = A.B^T.
// EPI==0: BM=256,BN=256, grid 512. P = exp2(scale*S) -> Pout bf16 + row sums.
// EPI==1: BM=128,BN=256, grid 256. C = S / lin[row] -> Cout fp32.
// Phase p: {frag ds_reads | 1 staging unit issue} BAR {setprio1 16xMFMA
// setprio0} [tile end: vmcnt(4)] BAR. Compiler freely interleaves its counted
// lgkm waits + MFMA within the phase (r109); "memory"-clobber barriers keep
// all memory ops inside their phase, preserving the WAR/RAW proof:
//   - A(g+1) staged p0/p1 into buf[g^1]; B(g+2) staged p2/p3 into buf[g&1]
//     (B(g) units of that buffer were last read at p0, phases are barrier-
//     bounded, so no overwrite race).
//   - vmcnt(4) at tile end leaves exactly B(g+2)'s 4 loads in flight; A(g+1),
//     B(g+1) are drained before buf[g^1] is read.
template <int EPI>
__global__ __launch_bounds__(512, 2) void gemm8p(
    const unsigned short* __restrict__ A, const unsigned short* __restrict__ B,
    unsigned short* __restrict__ Pout, float* __restrict__ lsum,
    float* __restrict__ Cout, const float* __restrict__ lin, float scale) {
  constexpr int BM = EPI ? 128 : 256;
  constexpr int Kd = EPI ? 4096 : 1024;
  constexpr int Nc = EPI ? 1024 : 4096;
  constexpr int NT = Kd / 64;             // 16 / 64 K-tiles (pow2)
  constexpr int AU = BM / 128;            // A 16KB units per tile (2 / 1)
  constexpr int NU = AU + 2;              // + 2 B units
  constexpr int M_rep = BM / 32;          // 8 / 4
  constexpr int PH = M_rep / 2;           // 4 / 2 phases per tile

  __shared__ __align__(16) char lds[2 * NU * 16384];   // 128 / 96 KB

  const int tid = threadIdx.x;
  const int lane = tid & 63;
  const int w = tid >> 6;
  const int wm = w >> 2;
  const int wn = w & 3;
  const int q = lane >> 4;
  const int ml = lane & 15;

  const int bid = blockIdx.x;
  const int wg = (bid & 7) * (EPI ? 32 : 64) + (bid >> 3);
  const int m_t = EPI ? (wg >> 2) : (wg >> 4);
  const int n_t = EPI ? (wg & 3) : (wg & 15);
  const int row0 = m_t * BM;
  const int col0 = n_t * 256;

  // staging: chunk c -> row r=c>>3; LDS slot s=c&7 holds global k-chunk
  // s^(r&7). LDS dest is wave-uniform (HW adds lane*16).
  const int cr = tid >> 3;
  const int ss = (tid & 7) ^ (cr & 7);
  char* ldsw = lds + w * 1024;

  const int ccB = (q ^ (ml & 7)) * 16;
  const int aOff = (EPI ? 0 : wm) * 16384 + ((EPI ? wm * 64 : 0) + ml) * 128 + ccB;
  const int bOff = (AU + (wn >> 1)) * 16384 + ((wn & 1) * 64 + ml) * 128 + ccB;

  f32x4 acc[M_rep][4] = {};

  auto stA = [&](int a, int t, int buf) {
    const unsigned short* s = A + (size_t)(row0 + a * 128 + cr) * Kd + t * 64 + ss * 8;
    char* d = ldsw + (buf * NU + a) * 16384;
    gld_lds16(s, d);
    gld_lds16(s + (size_t)64 * Kd, d + 8192);
  };
  auto stB = [&](int b, int t, int buf) {
    const unsigned short* s = B + (size_t)(col0 + b * 128 + cr) * Kd + t * 64 + ss * 8;
    char* d = ldsw + (buf * NU + AU + b) * 16384;
    gld_lds16(s, d);
    gld_lds16(s + (size_t)64 * Kd, d + 8192);
  };

  // Prologue: tile0 fully + B(1); drain tile0 (vmcnt leaves B(1) in flight).
#pragma unroll
  for (int a = 0; a < AU; ++a) stA(a, 0, 0);
  stB(0, 0, 0); stB(1, 0, 0);
  stB(0, 1, 1); stB(1, 1, 1);
  asm volatile("s_waitcnt vmcnt(4)" ::: "memory");
  BAR();

  for (int g = 0; g < NT; ++g) {
    const char* base = lds + (g & 1) * (NU * 16384);
    const int tA = (g + 1) & (NT - 1);
    const int bufA = (g + 1) & 1;
    const int tB = (g + 2) & (NT - 1);
    const int bufB = g & 1;

    bf16x8 bF[4][2];
#pragma unroll
    for (int ni = 0; ni < 4; ++ni)
#pragma unroll
      for (int ks = 0; ks < 2; ++ks)
        bF[ni][ks] = *(const bf16x8*)(base + (bOff ^ (ks * 64)) + ni * 2048);

#pragma unroll
    for (int p = 0; p < PH; ++p) {
      bf16x8 aF[2][2];
#pragma unroll
      for (int i = 0; i < 2; ++i)
#pragma unroll
        for (int ks = 0; ks < 2; ++ks)
          aF[i][ks] = *(const bf16x8*)(base + ((aOff ^ (ks * 64)) + (2 * p + i) * 2048));

      // staging schedule (one unit per phase; EPI1 packs B into its last phase)
      if constexpr (EPI == 0) {
        if (p == 0) stA(0, tA, bufA);
        else if (p == 1) stA(1, tA, bufA);
        else if (p == 2) stB(0, tB, bufB);
        else stB(1, tB, bufB);
      } else {
        if (p == 0) stA(0, tA, bufA);
        else { stB(0, tB, bufB); stB(1, tB, bufB); }
      }

      BAR();
      __builtin_amdgcn_s_setprio(1);
#pragma unroll
      for (int ks = 0; ks < 2; ++ks)
#pragma unroll
        for (int i = 0; i < 2; ++i)
#pragma unroll
          for (int ni = 0; ni < 4; ++ni)
            acc[2 * p + i][ni] = __builtin_amdgcn_mfma_f32_16x16x32_bf16(
                aF[i][ks], bF[ni][ks], acc[2 * p + i][ni], 0, 0, 0);
      __builtin_amdgcn_s_setprio(0);
      if (p == PH - 1) asm volatile("s_waitcnt vmcnt(4)" ::: "memory");
      BAR();
    }
  }

  if constexpr (EPI == 0) {
#pragma unroll
    for (int mi = 0; mi < M_rep; ++mi) {
#pragma unroll
      for (int j = 0; j < 4; ++j) {
        const int gr = row0 + wm * (BM / 2) + mi * 16 + q * 4 + j;
        float rsum = 0.f;
#pragma unroll
        for (int ni = 0; ni < 4; ++ni) {
          const int gc = col0 + wn * 64 + ni * 16 + ml;
          float pv = exp2f(acc[mi][ni][j] * scale);  // scale includes log2(e)
          rsum += pv;
          Pout[(size_t)gr * Nc + gc] = f2bf(pv);
        }
        rsum += __shfl_xor(rsum, 1);
        rsum += __shfl_xor(rsum, 2);
        rsum += __shfl_xor(rsum, 4);
        rsum += __shfl_xor(rsum, 8);
        if (ml == 0) atomicAdd(&lsum[gr], rsum);
      }
    }
  } else {
#pragma unroll
    for (int mi = 0; mi < M_rep; ++mi) {
#pragma unroll
      for (int j = 0; j < 4; ++j) {
        const int gr = row0 + wm * (BM / 2) + mi * 16 + q * 4 + j;
        const float rl = 1.0f / lin[gr];
#pragma unroll
        for (int ni = 0; ni < 4; ++ni) {
          const int gc = col0 + wn * 64 + ni * 16 + ml;
          Cout[(size_t)gr * Nc + gc] = acc[mi][ni][j] * rl;
        }
      }
    }
  }
}

extern "C" void kernel_launch(void* const* d_in, const int* in_sizes, int n_in,
                              void* d_out, int out_size, void* d_ws,
                              size_t ws_size, hipStream_t stream) {
  const float* x = (const float*)d_in[0];   // [8192,1024]
  const float* Kw = (const float*)d_in[1];  // [4096,1024]
  const float* Vw = (const float*)d_in[2];  // [4096,1024]
  float* out = (float*)d_out;               // [8192,1024]
  char* ws = (char*)d_ws;

  unsigned short* x16  = (unsigned short*)(ws);                   // 16 MB
  unsigned short* K16  = (unsigned short*)(ws + (16u << 20));     //  8 MB
  unsigned short* V16t = (unsigned short*)(ws + (24u << 20));     //  8 MB
  float*          lsum = (float*)(ws + (32u << 20));              // 32 KB
  unsigned short* P16  = (unsigned short*)(ws + (33u << 20));     // 64 MB

  cvt_all<<<7168, 256, 0, stream>>>(x, x16, Kw, K16, Vw, V16t, lsum);

  // GEMM1: P = exp(x16 . K16^T / 32), row sums -> lsum.
  gemm8p<0><<<512, 512, 0, stream>>>(
      x16, K16, P16, lsum, nullptr, nullptr,
      0.03125f * 1.44269504088896340736f);
  // GEMM2: out = (P16 . V16t^T) / lsum[row]
  gemm8p<1><<<256, 512, 0, stream>>>(
      P16, V16t, nullptr, nullptr, out, lsum, 0.f);
}